// Round 1
// baseline (82.299 us; speedup 1.0000x reference)
//
#include <hip/hip_runtime.h>

#define BS 16384
#define D  512
#define MARGIN 1.0f

#define RPW 8                  // rows per wave (was 4) -> 48 float4 loads in flight
#define WPB 4                  // waves per block (256 threads)
#define RPB (RPW * WPB)        // 32 rows per block
#define NBLK (BS / RPB)        // 512 blocks = exactly 2 blocks/CU, one round

// Stage 1: per-block partial sums of relu(d_ap - d_an + margin).
// Structure: (1) preload all 24 wave-uniform indices -> scalar loads, row
// bases in SGPRs; (2) issue all 48 float4 loads back-to-back (double the
// in-flight bytes of the RPW=4 version, same 8-waves/CU occupancy tier);
// (3) FMA into 8 independent accumulators; (4) interleave the 8 shuffle
// chains so cross-lane latency overlaps 8-wide.
// __launch_bounds__(256, 2): 2 waves/EU min -> allocator capped at 256 VGPR,
// 2 blocks/CU resident. Expect ~210-230 VGPR, no spill.
__global__ __launch_bounds__(256, 2) void triplet_partial(
    const float* __restrict__ batch,
    const int*   __restrict__ triplets,
    float* __restrict__ partial)
{
    const int lane = threadIdx.x & 63;
    const int wib  = threadIdx.x >> 6;
    const int rowBase = (blockIdx.x * WPB + wib) * RPW;

    __shared__ float s_part[WPB];

    // (1) preload indices (wave-uniform -> s_load_dwordx8 x3: 24 contiguous ints)
    int t0[RPW], t1[RPW], t2[RPW];
    #pragma unroll
    for (int r = 0; r < RPW; ++r) {
        t0[r] = triplets[(rowBase + r) * 3 + 0];
        t1[r] = triplets[(rowBase + r) * 3 + 1];
        t2[r] = triplets[(rowBase + r) * 3 + 2];
    }

    // (2) issue all loads: 8 rows x 3 ptrs x 2 chunks = 48 float4
    float4 av[RPW][2], pv[RPW][2], nv[RPW][2];
    #pragma unroll
    for (int r = 0; r < RPW; ++r) {
        const float4* __restrict__ a = (const float4*)(batch + (size_t)t0[r] * D);
        const float4* __restrict__ p = (const float4*)(batch + (size_t)t1[r] * D);
        const float4* __restrict__ n = (const float4*)(batch + (size_t)t2[r] * D);
        #pragma unroll
        for (int k = 0; k < 2; ++k) {
            const int j = lane + 64 * k;     // D/4 = 128 float4 per row
            av[r][k] = a[j];
            pv[r][k] = p[j];
            nv[r][k] = n[j];
        }
    }

    // (3) per-lane partials: sum((a-p)^2 - (a-n)^2), one acc per row
    float acc[RPW];
    #pragma unroll
    for (int r = 0; r < RPW; ++r) {
        float s = 0.0f;
        #pragma unroll
        for (int k = 0; k < 2; ++k) {
            float dp, dn;
            dp = av[r][k].x - pv[r][k].x; dn = av[r][k].x - nv[r][k].x; s += dp * dp - dn * dn;
            dp = av[r][k].y - pv[r][k].y; dn = av[r][k].y - nv[r][k].y; s += dp * dp - dn * dn;
            dp = av[r][k].z - pv[r][k].z; dn = av[r][k].z - nv[r][k].z; s += dp * dp - dn * dn;
            dp = av[r][k].w - pv[r][k].w; dn = av[r][k].w - nv[r][k].w; s += dp * dp - dn * dn;
        }
        acc[r] = s;
    }

    // (4) interleaved wave reductions: 8 independent cross-lane chains per level
    #pragma unroll
    for (int off = 32; off > 0; off >>= 1) {
        #pragma unroll
        for (int r = 0; r < RPW; ++r)
            acc[r] += __shfl_down(acc[r], off, 64);
    }

    if (lane == 0) {
        float waveLoss = 0.0f;
        #pragma unroll
        for (int r = 0; r < RPW; ++r) {
            const float loss = acc[r] + MARGIN;
            waveLoss += (loss > 0.0f) ? loss : 0.0f;
        }
        s_part[wib] = waveLoss;
    }
    __syncthreads();
    if (threadIdx.x == 0)
        partial[blockIdx.x] = s_part[0] + s_part[1] + s_part[2] + s_part[3];
}

// Stage 2: reduce NBLK=512 partials -> out[0]. Single wave, deterministic.
__global__ __launch_bounds__(64) void triplet_reduce(
    const float* __restrict__ partial,
    float* __restrict__ out)
{
    const int lane = threadIdx.x;            // 64 threads, 1 wave

    // 512 floats = 128 float4: each lane reads 2
    const float4* p4 = (const float4*)partial;
    const float4 a = p4[lane];
    const float4 b = p4[lane + 64];
    float acc = (a.x + a.y + a.z + a.w) + (b.x + b.y + b.z + b.w);

    #pragma unroll
    for (int off = 32; off > 0; off >>= 1)
        acc += __shfl_down(acc, off, 64);

    if (lane == 0)
        out[0] = acc;
}

extern "C" void kernel_launch(void* const* d_in, const int* in_sizes, int n_in,
                              void* d_out, int out_size, void* d_ws, size_t ws_size,
                              hipStream_t stream) {
    const float* batch    = (const float*)d_in[0];
    const int*   triplets = (const int*)d_in[1];
    float*       out      = (float*)d_out;
    float*       partial  = (float*)d_ws;    // NBLK floats = 2 KB scratch

    triplet_partial<<<NBLK, 256, 0, stream>>>(batch, triplets, partial);
    triplet_reduce<<<1, 64, 0, stream>>>(partial, out);
}